// Round 8
// baseline (336.207 us; speedup 1.0000x reference)
//
#include <hip/hip_runtime.h>
#include <hip/hip_fp16.h>

// out[M,N] = fp16( a[M,K] @ (w_q[K,N] * scale[K/G,N]) ), G=128, all dims 4096.
// Harness dtype contract: fp16 tensors passed/returned as FLOAT32.
// 2-dispatch: fused prep (A f32->f16 + W dequant/transpose -> Wt f16 [N][K]),
// then 128x128x64 GEMM with v_mfma_f32_32x32x16_f16 (2x2 tiles/wave),
// global_load_lds staging, XOR-swizzled LDS (measured 0 bank conflicts).
#define MDIM 4096
#define NDIM 4096
#define KDIM 4096

#define BM 128
#define BN 128
#define BK 64
#define NT 256

typedef _Float16 f16x8 __attribute__((ext_vector_type(8)));
typedef float f32x16 __attribute__((ext_vector_type(16)));
typedef float f32x4 __attribute__((ext_vector_type(4)));
typedef unsigned int u32;
typedef unsigned short u16;

__device__ inline __half2 as_half2(u32 u) { return __builtin_bit_cast(__half2, u); }
__device__ inline u32 as_u32(__half2 h) { return __builtin_bit_cast(u32, h); }
__device__ inline u32 pkrtz(float a, float b) {
  return __builtin_bit_cast(u32, __builtin_amdgcn_cvt_pkrtz(a, b));
}

// async global -> LDS, 16 B/lane. LDS dst must be wave-uniform base + lane*16.
__device__ inline void load16_to_lds(const void* g, void* l) {
  __builtin_amdgcn_global_load_lds(
      (__attribute__((address_space(1))) const u32*)g,
      (__attribute__((address_space(3))) u32*)l,
      16, 0, 0);
}

// ---- fused prep: blocks [0,1024) W dequant+transpose; [1024,2048) A conv ----
#define TSTR 68
__global__ __launch_bounds__(NT) void prep(const float* __restrict__ A,
                                           _Float16* __restrict__ A16,
                                           const int* __restrict__ Wq,
                                           const float* __restrict__ Sc,
                                           _Float16* __restrict__ Wt) {
  __shared__ __align__(16) u16 Ls[4][64 * TSTR];
  const int tid = threadIdx.x;

  if (blockIdx.x >= 1024) {
    // ---- A fp32 -> fp16, deep stream: 8 independent chunks/thread ----
    const int t = (blockIdx.x - 1024) * NT + tid;  // 0..262143
#pragma unroll
    for (int i = 0; i < 8; ++i) {
      const size_t base = ((size_t)i * 262144 + t) * 8;
      const float4 f0 = *(const float4*)(A + base);
      const float4 f1 = *(const float4*)(A + base + 4);
      u32 pk[4];
      pk[0] = pkrtz(f0.x, f0.y);
      pk[1] = pkrtz(f0.z, f0.w);
      pk[2] = pkrtz(f1.x, f1.y);
      pk[3] = pkrtz(f1.z, f1.w);
      *(uint4*)(A16 + base) = *(const uint4*)pk;
    }
    return;
  }

  // ---- W dequant + transpose, 4 k-tiles (256 k) per block ----
  const int n0 = (blockIdx.x & 63) * 64;
  const int kb = (blockIdx.x >> 6) * 256;
  const int col4 = (tid & 15) * 4;
  const int qrow = tid >> 4;  // 0..15

  int4 v[16];
#pragma unroll
  for (int t = 0; t < 4; ++t)
#pragma unroll
    for (int r = 0; r < 4; ++r)
      v[t * 4 + r] = *(const int4*)(Wq + (size_t)(kb + t * 64 + r * 16 + qrow) * NDIM +
                                    n0 + col4);
  float4 s[2];
  s[0] = *(const float4*)(Sc + (size_t)(kb >> 7) * NDIM + n0 + col4);
  s[1] = *(const float4*)(Sc + (size_t)((kb >> 7) + 1) * NDIM + n0 + col4);

#pragma unroll
  for (int t = 0; t < 4; ++t) {
    const float4 sf = s[t >> 1];
    __half2 s01 = __floats2half2_rn(sf.x, sf.y);
    __half2 s23 = __floats2half2_rn(sf.z, sf.w);
    const __half2 kneg = __half2half2(__float2half(-1024.0f));
    __half2 nb01 = __hmul2(s01, kneg), nb23 = __hmul2(s23, kneg);
#pragma unroll
    for (int r = 0; r < 4; ++r) {
      const int4 vv = v[t * 4 + r];
      // fp16 bits of (1024+v): 0x6400|v; hfma gives single-rounded v*s.
      u32 u01 = (u32)vv.x | ((u32)vv.y << 16) | 0x64006400u;
      u32 u23 = (u32)vv.z | ((u32)vv.w << 16) | 0x64006400u;
      u32 pk[2];
      pk[0] = as_u32(__hfma2(as_half2(u01), s01, nb01));
      pk[1] = as_u32(__hfma2(as_half2(u23), s23, nb23));
      *(uint2*)&Ls[t][(size_t)(r * 16 + qrow) * TSTR + col4] = *(const uint2*)pk;
    }
  }
  __syncthreads();

#pragma unroll
  for (int t = 0; t < 4; ++t)
#pragma unroll
    for (int r2 = 0; r2 < 2; ++r2) {
      const int idx = r2 * 256 + tid;
      const int n = idx >> 3;
      const int kc = (idx & 7) * 8;
      u16 tmp[8];
#pragma unroll
      for (int j = 0; j < 8; ++j) tmp[j] = Ls[t][(size_t)(kc + j) * TSTR + n];
      *(uint4*)(Wt + (size_t)(n0 + n) * KDIM + kb + t * 64 + kc) =
          *(const uint4*)tmp;
    }
}

// -------- GEMM: 32x32x16 MFMA, 2x2 tiles/wave, XOR-swizzled LDS ----------
// A/B operand: [dim=lane&31][k=(lane>>5)*8+j]; C/D: n=lane&31,
// m=(reg&3)+8*(reg>>2)+4*(lane>>5)  [HW-verified m74/m101].
__global__ __launch_bounds__(NT) void gemm_f16(const _Float16* __restrict__ A16,
                                               const _Float16* __restrict__ Wt,
                                               float* __restrict__ C) {
  __shared__ __align__(16) _Float16 As[BM * BK];
  __shared__ __align__(16) _Float16 Bs[BN * BK];

  const int tid = threadIdx.x;
  const int bx = blockIdx.x & 31;
  const int by = blockIdx.x >> 5;
  const int m_base = by * BM;
  const int n_base = bx * BN;

  const int wave = tid >> 6;
  const int lane = tid & 63;
  const int l31 = lane & 31;
  const int half = lane >> 5;  // 0/1
  const int wm = (wave & 1) * 64;
  const int wn = (wave >> 1) * 64;

  f32x16 acc[2][2];
#pragma unroll
  for (int i = 0; i < 2; ++i)
#pragma unroll
    for (int j = 0; j < 2; ++j) acc[i][j] = (f32x16)0.0f;

  for (int kt = 0; kt < KDIM / BK; ++kt) {
    const int k0 = kt * BK;
    __syncthreads();

    // stage A and B via global_load_lds with XOR-swizzled source column:
    // physical chunk c holds logical chunk (c&7)^(row&7).
#pragma unroll
    for (int r = 0; r < 4; ++r) {
      const int c = r * 256 + tid;           // physical chunk 0..1023
      const int row = c >> 3;
      const int gcol = (c & 7) ^ (row & 7);  // logical (global) chunk
      load16_to_lds(A16 + (size_t)(m_base + row) * KDIM + k0 + gcol * 8,
                    (char*)As + (size_t)c * 16);
      load16_to_lds(Wt + (size_t)(n_base + row) * KDIM + k0 + gcol * 8,
                    (char*)Bs + (size_t)c * 16);
    }
    __syncthreads();

#pragma unroll
    for (int ks = 0; ks < BK; ks += 16) {
      const int ckb = (ks >> 3) + half;  // logical 8-half chunk, 0..7
      f16x8 af[2], bf[2];
#pragma unroll
      for (int i = 0; i < 2; ++i) {
        const int row = wm + i * 32 + l31;
        af[i] = *(const f16x8*)&As[((size_t)row * 8 + (ckb ^ (row & 7))) * 8];
      }
#pragma unroll
      for (int j = 0; j < 2; ++j) {
        const int row = wn + j * 32 + l31;
        bf[j] = *(const f16x8*)&Bs[((size_t)row * 8 + (ckb ^ (row & 7))) * 8];
      }
#pragma unroll
      for (int i = 0; i < 2; ++i)
#pragma unroll
        for (int j = 0; j < 2; ++j)
          acc[i][j] = __builtin_amdgcn_mfma_f32_32x32x16_f16(af[i], bf[j],
                                                             acc[i][j], 0, 0, 0);
    }
  }

  // epilogue: n=lane&31, m=(reg&3)+8*(reg>>2)+4*half; fp16-round, store f32
#pragma unroll
  for (int i = 0; i < 2; ++i) {
#pragma unroll
    for (int j = 0; j < 2; ++j) {
      const int col = n_base + wn + j * 32 + l31;
#pragma unroll
      for (int reg = 0; reg < 16; ++reg) {
        const int row = m_base + wm + i * 32 + (reg & 3) + 4 * half + 8 * (reg >> 2);
        C[(size_t)row * NDIM + col] = __half2float(__float2half(acc[i][j][reg]));
      }
    }
  }
}

// ---------------- fallback: fused single-kernel (round-3, 331 us) --------
#define STR 72
__global__ __launch_bounds__(NT) void qgemm_fused(
    const float* __restrict__ A, const int* __restrict__ Wq,
    const float* __restrict__ Sc, float* __restrict__ C) {
  __shared__ __align__(16) _Float16 As[BM * STR];
  __shared__ __align__(16) _Float16 Bs[BN * STR];
  const int tid = threadIdx.x;
  const int bx = blockIdx.x & 31, by = blockIdx.x >> 5;
  const int m_base = by * BM, n_base = bx * BN;
  const int wave = tid >> 6, lane = tid & 63;
  const int l15 = lane & 15, quad = lane >> 4;
  const int wm = (wave & 1) * 64, wn = (wave >> 1) * 64;
  const int bn_local = tid & 127, bk_half = (tid >> 7) * 8;
  const int gn = n_base + bn_local;
  f32x4 acc[4][4];
#pragma unroll
  for (int i = 0; i < 4; ++i)
#pragma unroll
    for (int j = 0; j < 4; ++j) acc[i][j] = (f32x4)0.0f;
  typedef _Float16 f16x8l __attribute__((ext_vector_type(8)));
  for (int kt = 0; kt < KDIM / BK; ++kt) {
    const int k0 = kt * BK;
    __syncthreads();
#pragma unroll
    for (int i = 0; i < 8; ++i) {
      const int c = i * 256 + tid;
      const int row = c >> 4, col4 = (c & 15) * 4;
      const float4 f = *(const float4*)(A + (size_t)(m_base + row) * KDIM + k0 + col4);
      u32 pk[2];
      pk[0] = pkrtz(f.x, f.y);
      pk[1] = pkrtz(f.z, f.w);
      *(uint2*)&As[(size_t)row * STR + col4] = *(const uint2*)pk;
    }
    {
      const __half hs = __float2half(Sc[(size_t)(k0 >> 7) * NDIM + gn]);
      const __half2 s2 = __half2half2(hs);
      const __half2 nb2 = __half2half2(__hmul(hs, __float2half(-1024.0f)));
#pragma unroll
      for (int it = 0; it < 4; ++it) {
        const int k = bk_half + it * 16;
        u32 v[8];
#pragma unroll
        for (int j = 0; j < 8; ++j)
          v[j] = (u32)Wq[(size_t)(k0 + k + j) * NDIM + gn];
        u32 pk[4];
#pragma unroll
        for (int p = 0; p < 4; ++p) {
          u32 u = v[2 * p] | (v[2 * p + 1] << 16) | 0x64006400u;
          pk[p] = as_u32(__hfma2(as_half2(u), s2, nb2));
        }
        *(uint4*)&Bs[(size_t)bn_local * STR + k] = *(const uint4*)pk;
      }
    }
    __syncthreads();
#pragma unroll
    for (int ks = 0; ks < BK; ks += 32) {
      f16x8l af[4], bf[4];
#pragma unroll
      for (int i = 0; i < 4; ++i)
        af[i] = *(const f16x8l*)&As[(size_t)(wm + i * 16 + l15) * STR + ks + quad * 8];
#pragma unroll
      for (int j = 0; j < 4; ++j)
        bf[j] = *(const f16x8l*)&Bs[(size_t)(wn + j * 16 + l15) * STR + ks + quad * 8];
#pragma unroll
      for (int i = 0; i < 4; ++i)
#pragma unroll
        for (int j = 0; j < 4; ++j)
          acc[i][j] = __builtin_amdgcn_mfma_f32_16x16x32_f16(af[i], bf[j],
                                                             acc[i][j], 0, 0, 0);
    }
  }
#pragma unroll
  for (int i = 0; i < 4; ++i)
#pragma unroll
    for (int j = 0; j < 4; ++j) {
      const int col = n_base + wn + j * 16 + l15;
#pragma unroll
      for (int r = 0; r < 4; ++r) {
        const int row = m_base + wm + i * 16 + quad * 4 + r;
        C[(size_t)row * NDIM + col] = __half2float(__float2half(acc[i][j][r]));
      }
    }
}

extern "C" void kernel_launch(void* const* d_in, const int* in_sizes, int n_in,
                              void* d_out, int out_size, void* d_ws, size_t ws_size,
                              hipStream_t stream) {
  const float* a = (const float*)d_in[0];
  const int* wq = (const int*)d_in[1];
  const float* sc = (const float*)d_in[2];
  float* out = (float*)d_out;

  const size_t a16_bytes = (size_t)MDIM * KDIM * 2;  // 32 MiB
  const size_t wt_bytes = (size_t)NDIM * KDIM * 2;   // 32 MiB

  if (ws_size >= a16_bytes + wt_bytes) {
    _Float16* a16 = (_Float16*)d_ws;
    _Float16* wt = (_Float16*)((char*)d_ws + a16_bytes);
    prep<<<2048, NT, 0, stream>>>(a, a16, wq, sc, wt);
    gemm_f16<<<(MDIM / BM) * (NDIM / BN), NT, 0, stream>>>(a16, wt, out);
  } else {
    qgemm_fused<<<(MDIM / BM) * (NDIM / BN), NT, 0, stream>>>(a, wq, sc, out);
  }
}

// Round 9
// 327.131 us; speedup vs baseline: 1.0277x; 1.0277x over previous
//
#include <hip/hip_runtime.h>
#include <hip/hip_fp16.h>

// out[M,N] = fp16( a[M,K] @ (w_q[K,N] * scale[K/G,N]) ), G=128, all dims 4096.
// Harness dtype contract: fp16 tensors passed/returned as FLOAT32.
// 2-dispatch: shallow fused prep (A f32->f16 + W dequant/transpose -> Wt
// [N][K], R6-measured best), then 128x128x64 GEMM with
// v_mfma_f32_32x32x16_f16 (2x2/wave, R8-measured best), global_load_lds
// staging, XOR-swizzled LDS.
#define MDIM 4096
#define NDIM 4096
#define KDIM 4096

#define BM 128
#define BN 128
#define BK 64
#define NT 256

typedef _Float16 f16x8 __attribute__((ext_vector_type(8)));
typedef float f32x16 __attribute__((ext_vector_type(16)));
typedef float f32x4 __attribute__((ext_vector_type(4)));
typedef unsigned int u32;
typedef unsigned short u16;

__device__ inline __half2 as_half2(u32 u) { return __builtin_bit_cast(__half2, u); }
__device__ inline u32 as_u32(__half2 h) { return __builtin_bit_cast(u32, h); }
__device__ inline u32 pkrtz(float a, float b) {
  return __builtin_bit_cast(u32, __builtin_amdgcn_cvt_pkrtz(a, b));
}

// async global -> LDS, 16 B/lane. LDS dst must be wave-uniform base + lane*16.
__device__ inline void load16_to_lds(const void* g, void* l) {
  __builtin_amdgcn_global_load_lds(
      (__attribute__((address_space(1))) const u32*)g,
      (__attribute__((address_space(3))) u32*)l,
      16, 0, 0);
}

// ---- shallow fused prep (R6-measured best): blocks [0,4096) W 64x64
// dequant+transpose tiles; [4096,12288) A f32->f16 one 8-elem chunk/thread.
#define TSTR 68
#define WBLK 4096
__global__ __launch_bounds__(NT) void prep(const float* __restrict__ A,
                                           _Float16* __restrict__ A16,
                                           const int* __restrict__ Wq,
                                           const float* __restrict__ Sc,
                                           _Float16* __restrict__ Wt) {
  __shared__ __align__(16) u16 Ls[64 * TSTR];
  const int tid = threadIdx.x;

  if (blockIdx.x >= WBLK) {
    // ---- A fp32 -> fp16 (exact: values are fp16-representable) ----
    const size_t b = blockIdx.x - WBLK;
    const size_t base = (b * NT + tid) * 8;
    const float4 f0 = *(const float4*)(A + base);
    const float4 f1 = *(const float4*)(A + base + 4);
    u32 pk[4];
    pk[0] = pkrtz(f0.x, f0.y);
    pk[1] = pkrtz(f0.z, f0.w);
    pk[2] = pkrtz(f1.x, f1.y);
    pk[3] = pkrtz(f1.z, f1.w);
    *(uint4*)(A16 + base) = *(const uint4*)pk;
    return;
  }

  // ---- W: dequant Wq [K][N] + transpose -> Wt f16 [N][K], 64x64 tile ----
  const int n0 = (blockIdx.x & 63) * 64;
  const int k0 = (blockIdx.x >> 6) * 64;
  const int g = k0 >> 7;  // 64-tile lies within one 128-group

  // phase 1: coalesced read + dequant, LDS [k][n]
#pragma unroll
  for (int r = 0; r < 4; ++r) {
    const int c = r * 256 + tid;
    const int krow = c >> 4;
    const int col4 = (c & 15) * 4;
    const int4 v = *(const int4*)(Wq + (size_t)(k0 + krow) * NDIM + n0 + col4);
    const float4 s = *(const float4*)(Sc + (size_t)g * NDIM + n0 + col4);
    // fp16 bits of (1024+v): 0x6400|v; hfma gives single-rounded v*s.
    __half2 s01 = __floats2half2_rn(s.x, s.y);
    __half2 s23 = __floats2half2_rn(s.z, s.w);
    const __half2 kneg = __half2half2(__float2half(-1024.0f));
    __half2 nb01 = __hmul2(s01, kneg), nb23 = __hmul2(s23, kneg);
    u32 u01 = (u32)v.x | ((u32)v.y << 16) | 0x64006400u;
    u32 u23 = (u32)v.z | ((u32)v.w << 16) | 0x64006400u;
    u32 pk[2];
    pk[0] = as_u32(__hfma2(as_half2(u01), s01, nb01));
    pk[1] = as_u32(__hfma2(as_half2(u23), s23, nb23));
    *(uint2*)&Ls[(size_t)krow * TSTR + col4] = *(const uint2*)pk;
  }
  __syncthreads();

  // phase 2: transposed read from LDS, coalesced 16B writes to Wt [n][k]
#pragma unroll
  for (int r = 0; r < 2; ++r) {
    const int idx = r * 256 + tid;
    const int n = idx >> 3;
    const int kc = (idx & 7) * 8;
    u16 tmp[8];
#pragma unroll
    for (int j = 0; j < 8; ++j) tmp[j] = Ls[(size_t)(kc + j) * TSTR + n];
    *(uint4*)(Wt + (size_t)(n0 + n) * KDIM + k0 + kc) = *(const uint4*)tmp;
  }
}

// -------- GEMM: 32x32x16 MFMA, 2x2 tiles/wave, XOR-swizzled LDS ----------
// (R8-measured: 173.5 us, MfmaUtil 35.5, VALUBusy 9.7)
// A/B operand: [dim=lane&31][k=(lane>>5)*8+j]; C/D: n=lane&31,
// m=(reg&3)+8*(reg>>2)+4*(lane>>5)  [HW-verified m74/m101].
__global__ __launch_bounds__(NT) void gemm_f16(const _Float16* __restrict__ A16,
                                               const _Float16* __restrict__ Wt,
                                               float* __restrict__ C) {
  __shared__ __align__(16) _Float16 As[BM * BK];
  __shared__ __align__(16) _Float16 Bs[BN * BK];

  const int tid = threadIdx.x;
  const int bx = blockIdx.x & 31;
  const int by = blockIdx.x >> 5;
  const int m_base = by * BM;
  const int n_base = bx * BN;

  const int wave = tid >> 6;
  const int lane = tid & 63;
  const int l31 = lane & 31;
  const int half = lane >> 5;  // 0/1
  const int wm = (wave & 1) * 64;
  const int wn = (wave >> 1) * 64;

  f32x16 acc[2][2];
#pragma unroll
  for (int i = 0; i < 2; ++i)
#pragma unroll
    for (int j = 0; j < 2; ++j) acc[i][j] = (f32x16)0.0f;

  for (int kt = 0; kt < KDIM / BK; ++kt) {
    const int k0 = kt * BK;
    __syncthreads();

    // stage A and B via global_load_lds with XOR-swizzled source column:
    // physical chunk c holds logical chunk (c&7)^(row&7).
#pragma unroll
    for (int r = 0; r < 4; ++r) {
      const int c = r * 256 + tid;           // physical chunk 0..1023
      const int row = c >> 3;
      const int gcol = (c & 7) ^ (row & 7);  // logical (global) chunk
      load16_to_lds(A16 + (size_t)(m_base + row) * KDIM + k0 + gcol * 8,
                    (char*)As + (size_t)c * 16);
      load16_to_lds(Wt + (size_t)(n_base + row) * KDIM + k0 + gcol * 8,
                    (char*)Bs + (size_t)c * 16);
    }
    __syncthreads();

#pragma unroll
    for (int ks = 0; ks < BK; ks += 16) {
      const int ckb = (ks >> 3) + half;  // logical 8-half chunk, 0..7
      f16x8 af[2], bf[2];
#pragma unroll
      for (int i = 0; i < 2; ++i) {
        const int row = wm + i * 32 + l31;
        af[i] = *(const f16x8*)&As[((size_t)row * 8 + (ckb ^ (row & 7))) * 8];
      }
#pragma unroll
      for (int j = 0; j < 2; ++j) {
        const int row = wn + j * 32 + l31;
        bf[j] = *(const f16x8*)&Bs[((size_t)row * 8 + (ckb ^ (row & 7))) * 8];
      }
#pragma unroll
      for (int i = 0; i < 2; ++i)
#pragma unroll
        for (int j = 0; j < 2; ++j)
          acc[i][j] = __builtin_amdgcn_mfma_f32_32x32x16_f16(af[i], bf[j],
                                                             acc[i][j], 0, 0, 0);
    }
  }

  // epilogue: n=lane&31, m=(reg&3)+8*(reg>>2)+4*half; fp16-round, store f32
#pragma unroll
  for (int i = 0; i < 2; ++i) {
#pragma unroll
    for (int j = 0; j < 2; ++j) {
      const int col = n_base + wn + j * 32 + l31;
#pragma unroll
      for (int reg = 0; reg < 16; ++reg) {
        const int row = m_base + wm + i * 32 + (reg & 3) + 4 * half + 8 * (reg >> 2);
        C[(size_t)row * NDIM + col] = __half2float(__float2half(acc[i][j][reg]));
      }
    }
  }
}

// ---------------- fallback: fused single-kernel (round-3, 331 us) --------
#define STR 72
__global__ __launch_bounds__(NT) void qgemm_fused(
    const float* __restrict__ A, const int* __restrict__ Wq,
    const float* __restrict__ Sc, float* __restrict__ C) {
  __shared__ __align__(16) _Float16 As[BM * STR];
  __shared__ __align__(16) _Float16 Bs[BN * STR];
  const int tid = threadIdx.x;
  const int bx = blockIdx.x & 31, by = blockIdx.x >> 5;
  const int m_base = by * BM, n_base = bx * BN;
  const int wave = tid >> 6, lane = tid & 63;
  const int l15 = lane & 15, quad = lane >> 4;
  const int wm = (wave & 1) * 64, wn = (wave >> 1) * 64;
  const int bn_local = tid & 127, bk_half = (tid >> 7) * 8;
  const int gn = n_base + bn_local;
  f32x4 acc[4][4];
#pragma unroll
  for (int i = 0; i < 4; ++i)
#pragma unroll
    for (int j = 0; j < 4; ++j) acc[i][j] = (f32x4)0.0f;
  for (int kt = 0; kt < KDIM / BK; ++kt) {
    const int k0 = kt * BK;
    __syncthreads();
#pragma unroll
    for (int i = 0; i < 8; ++i) {
      const int c = i * 256 + tid;
      const int row = c >> 4, col4 = (c & 15) * 4;
      const float4 f = *(const float4*)(A + (size_t)(m_base + row) * KDIM + k0 + col4);
      u32 pk[2];
      pk[0] = pkrtz(f.x, f.y);
      pk[1] = pkrtz(f.z, f.w);
      *(uint2*)&As[(size_t)row * STR + col4] = *(const uint2*)pk;
    }
    {
      const __half hs = __float2half(Sc[(size_t)(k0 >> 7) * NDIM + gn]);
      const __half2 s2 = __half2half2(hs);
      const __half2 nb2 = __half2half2(__hmul(hs, __float2half(-1024.0f)));
#pragma unroll
      for (int it = 0; it < 4; ++it) {
        const int k = bk_half + it * 16;
        u32 v[8];
#pragma unroll
        for (int j = 0; j < 8; ++j)
          v[j] = (u32)Wq[(size_t)(k0 + k + j) * NDIM + gn];
        u32 pk[4];
#pragma unroll
        for (int p = 0; p < 4; ++p) {
          u32 u = v[2 * p] | (v[2 * p + 1] << 16) | 0x64006400u;
          pk[p] = as_u32(__hfma2(as_half2(u), s2, nb2));
        }
        *(uint4*)&Bs[(size_t)bn_local * STR + k] = *(const uint4*)pk;
      }
    }
    __syncthreads();
#pragma unroll
    for (int ks = 0; ks < BK; ks += 32) {
      f16x8 af[4], bf[4];
#pragma unroll
      for (int i = 0; i < 4; ++i)
        af[i] = *(const f16x8*)&As[(size_t)(wm + i * 16 + l15) * STR + ks + quad * 8];
#pragma unroll
      for (int j = 0; j < 4; ++j)
        bf[j] = *(const f16x8*)&Bs[(size_t)(wn + j * 16 + l15) * STR + ks + quad * 8];
#pragma unroll
      for (int i = 0; i < 4; ++i)
#pragma unroll
        for (int j = 0; j < 4; ++j)
          acc[i][j] = __builtin_amdgcn_mfma_f32_16x16x32_f16(af[i], bf[j],
                                                             acc[i][j], 0, 0, 0);
    }
  }
#pragma unroll
  for (int i = 0; i < 4; ++i)
#pragma unroll
    for (int j = 0; j < 4; ++j) {
      const int col = n_base + wn + j * 16 + l15;
#pragma unroll
      for (int r = 0; r < 4; ++r) {
        const int row = m_base + wm + i * 16 + quad * 4 + r;
        C[(size_t)row * NDIM + col] = __half2float(__float2half(acc[i][j][r]));
      }
    }
}

extern "C" void kernel_launch(void* const* d_in, const int* in_sizes, int n_in,
                              void* d_out, int out_size, void* d_ws, size_t ws_size,
                              hipStream_t stream) {
  const float* a = (const float*)d_in[0];
  const int* wq = (const int*)d_in[1];
  const float* sc = (const float*)d_in[2];
  float* out = (float*)d_out;

  const size_t a16_bytes = (size_t)MDIM * KDIM * 2;  // 32 MiB
  const size_t wt_bytes = (size_t)NDIM * KDIM * 2;   // 32 MiB

  if (ws_size >= a16_bytes + wt_bytes) {
    _Float16* a16 = (_Float16*)d_ws;
    _Float16* wt = (_Float16*)((char*)d_ws + a16_bytes);
    const int a_blocks = (MDIM * KDIM) / (NT * 8);  // 8192
    prep<<<WBLK + a_blocks, NT, 0, stream>>>(a, a16, wq, sc, wt);
    gemm_f16<<<(MDIM / BM) * (NDIM / BN), NT, 0, stream>>>(a16, wt, out);
  } else {
    qgemm_fused<<<(MDIM / BM) * (NDIM / BN), NT, 0, stream>>>(a, wq, sc, out);
  }
}